// Round 1
// baseline (640.387 us; speedup 1.0000x reference)
//
#include <hip/hip_runtime.h>

// Paste a masked 256x256 patch into a 32x3x1024x1024 background.
// out[b,c,i,j] = bg everywhere; in window [y,y+h)x[x,x+w): m*patch+(1-m)*bg.
// Memory-bound: ~855 MB total traffic -> ~136 us floor at 6.3 TB/s.

constexpr int B  = 32;
constexpr int C  = 3;
constexpr int H  = 1024;
constexpr int W  = 1024;
constexpr int PH = 256;
constexpr int PW = 256;
constexpr int VEC = 4;
constexpr int VPR = W / VEC;            // 256 float4 vectors per image row

__global__ __launch_bounds__(256) void paste_kernel(
    const float* __restrict__ bg,
    const float* __restrict__ patch,
    const int*   __restrict__ xs,
    const int*   __restrict__ ys,
    const float* __restrict__ mask,
    float*       __restrict__ out)
{
    const long long v = (long long)blockIdx.x * blockDim.x + threadIdx.x;
    // v indexes float4 vectors over (B,C,H,W/4); exact grid, no bounds check.
    const int jv  = (int)(v & (VPR - 1));   // vector col within row
    const long long row = v >> 8;           // global row over B*C*H
    const int i   = (int)(row & (H - 1));   // image row
    const int bc  = (int)(row >> 10);       // b*C + c
    const int b   = bc / C;
    const int c   = bc - b * C;

    const int j0 = jv * VEC;                // first column of this vector

    const float4 bgv = *reinterpret_cast<const float4*>(bg + v * VEC);
    float4 o = bgv;

    const int x  = xs[b];
    const int y  = ys[b];
    const int ri = i - y;                   // row inside patch
    if (ri >= 0 && ri < PH) {
        // does [j0, j0+4) overlap [x, x+PW)?
        if (j0 + VEC > x && j0 < x + PW) {
            const long long pbase = ((long long)(b * C + c) * PH + ri) * PW;
            float vals[VEC] = {o.x, o.y, o.z, o.w};
#pragma unroll
            for (int k = 0; k < VEC; ++k) {
                const int cj = j0 + k - x;  // col inside patch
                if (cj >= 0 && cj < PW) {
                    const float m = mask[pbase + cj];
                    const float p = patch[pbase + cj];
                    vals[k] = m * p + (1.0f - m) * vals[k];
                }
            }
            o = make_float4(vals[0], vals[1], vals[2], vals[3]);
        }
    }
    *reinterpret_cast<float4*>(out + v * VEC) = o;
}

extern "C" void kernel_launch(void* const* d_in, const int* in_sizes, int n_in,
                              void* d_out, int out_size, void* d_ws, size_t ws_size,
                              hipStream_t stream) {
    const float* bg    = (const float*)d_in[0];
    const float* patch = (const float*)d_in[1];
    const int*   xs    = (const int*)d_in[2];
    const int*   ys    = (const int*)d_in[3];
    const float* mask  = (const float*)d_in[4];
    float* out = (float*)d_out;

    const long long total_vecs = (long long)B * C * H * VPR;  // 25,165,824
    const int block = 256;
    const long long grid = total_vecs / block;                // 98,304
    hipLaunchKernelGGL(paste_kernel, dim3((unsigned)grid), dim3(block), 0, stream,
                       bg, patch, xs, ys, mask, out);
}